// Round 6
// baseline (428.760 us; speedup 1.0000x reference)
//
#include <hip/hip_runtime.h>
#include <hip/hip_bf16.h>
#include <cstdint>
#include <cstddef>

#define N_LEVELS   16
#define LOG2_T     19
#define TABLE_SIZE (1u << LOG2_T)
#define HASH_MASK  (TABLE_SIZE - 1u)
#define PRIME1     2654435761u

#define TPB 512
#define BT  64          // points per block

typedef __attribute__((ext_vector_type(8))) short short8;
typedef __attribute__((ext_vector_type(4))) float floatx4;
typedef __attribute__((ext_vector_type(2))) float f32x2;

// floor(16 * (2^(1/3))^l) in fp32 lands exactly on these integers
__device__ __forceinline__ constexpr float resf(int l) {
    constexpr float r[N_LEVELS] = {
        16.f, 20.f, 25.f, 32.f, 40.f, 50.f, 64.f, 80.f,
        101.f, 128.f, 161.f, 203.f, 256.f, 322.f, 406.f, 512.f
    };
    return r[l];
}

__device__ __forceinline__ unsigned short f2bf(float x) {
    union { float f; uint32_t u; } v; v.f = x;
    const uint32_t u = v.u;
    return (unsigned short)((u + 0x7fffu + ((u >> 16) & 1u)) >> 16);  // RNE
}

__device__ __forceinline__ uint32_t pk_bf16(float a, float b) {
#if __has_builtin(__builtin_amdgcn_cvt_pk_bf16_f32)
    typedef __attribute__((ext_vector_type(2))) __bf16 bf16x2;
    bf16x2 v = __builtin_amdgcn_cvt_pk_bf16_f32(a, b);
    uint32_t u; __builtin_memcpy(&u, &v, 4); return u;
#else
    return (uint32_t)f2bf(a) | ((uint32_t)f2bf(b) << 16);
#endif
}

// ---- XOR-swizzled LDS byte offsets ----
// NOTE (R5 lesson): banks wrap every 128 B; only byte bits 4-6 affect the
// 16B-granule bank group. ~2e7 SQ_LDS_BANK_CONFLICT is structural to wave64
// ds_read_b128 (64 lanes over 8 bank-groups) — swizzle keeps the per-
// quarter-wave pattern clean; don't chase the counter below this level.
__device__ __forceinline__ int fswz(int row, int cb) {   // feat: 128 B/row
    return (row << 7) + (cb ^ ((row & 7) << 4));
}
__device__ __forceinline__ int hswz(int row, int cb) {   // h: 512 B/row
    const int c = row & 7;
    return (row << 9) + (cb ^ ((c << 4) ^ (c << 6)));
}

// ---------------- weight packing into MFMA fragments ----------------
// Fragment for (tile, ktile): lane (q=l>>4, r=l&15) holds W[k = kt*32 + q*8 + j][col = tile*16 + r].
__global__ void pack_weights(const float* __restrict__ W0,
                             const float* __restrict__ W1,
                             const float* __restrict__ W2,
                             unsigned short* __restrict__ ws)
{
    const int f = blockIdx.x;       // 0..167
    const int lane = threadIdx.x;   // 0..63
    const int q = lane >> 4, r = lane & 15;
    int layer, kt, nt;
    if (f < 32)       { layer = 0; kt = f >> 4;        nt = f & 15; }
    else if (f < 160) { layer = 1; kt = (f - 32) >> 4; nt = (f - 32) & 15; }
    else              { layer = 2; kt = f - 160;       nt = 0; }
    unsigned short vals[8];
    #pragma unroll
    for (int j = 0; j < 8; ++j) {
        const int k = kt * 32 + q * 8 + j;
        const int n = nt * 16 + r;
        float v = 0.f;
        if (layer == 0) {
            // feat order: [enc0..enc31, x, y, zeros]; original W0 rows: [x, y, enc0..enc31]
            if (k < 32)       v = W0[(2 + k) * 256 + n];
            else if (k == 32) v = W0[0 * 256 + n];
            else if (k == 33) v = W0[1 * 256 + n];
        } else if (layer == 1) {
            v = W1[k * 256 + n];
        } else {
            if (n < 3) v = W2[k * 3 + n];
        }
        vals[j] = f2bf(v);
    }
    uint4 pk;
    pk.x = (uint32_t)vals[0] | ((uint32_t)vals[1] << 16);
    pk.y = (uint32_t)vals[2] | ((uint32_t)vals[3] << 16);
    pk.z = (uint32_t)vals[4] | ((uint32_t)vals[5] << 16);
    pk.w = (uint32_t)vals[6] | ((uint32_t)vals[7] << 16);
    *(uint4*)(ws + (size_t)f * 1024 + lane * 8) = pk;
}

// ---- phase-1 encode: 2 levels (2W, 2W+1) for one point, compile-time W ----
template<int W>
__device__ __forceinline__ uint2 encode2(float x, float y, const char* __restrict__ ebase)
{
    uint32_t vv[2];
    #pragma unroll
    for (int i = 0; i < 2; ++i) {
        const int l = 2 * W + i;
        const float res  = resf(l);
        const float grid = 2.0f / res;             // constexpr IEEE div (matches ref)
        const float invg = res * 0.5f;             // exact
        const float tx = (x + 1.0f) / grid;        // IEEE div feeds floor -> exact cell match
        const float ty = (y + 1.0f) / grid;
        const int bx = (int)floorf(tx);
        const int by = (int)floorf(ty);
        const float wx = (x - ((float)bx * grid - 1.0f)) * invg;
        const float wy = (y - ((float)by * grid - 1.0f)) * invg;
        const uint32_t hy0 = (uint32_t)by * PRIME1;
        const uint32_t hy1 = hy0 + PRIME1;         // (by+1)*P mod 2^32
        const uint32_t ux0 = (uint32_t)bx;
        const uint32_t ux1 = ux0 + 1u;
        const uint32_t lb = (uint32_t)l << (LOG2_T + 3);   // level table byte base
        const f32x2 e00 = *(const f32x2*)(ebase + (lb + (((ux0 ^ hy0) & HASH_MASK) << 3)));
        const f32x2 e01 = *(const f32x2*)(ebase + (lb + (((ux0 ^ hy1) & HASH_MASK) << 3)));
        const f32x2 e10 = *(const f32x2*)(ebase + (lb + (((ux1 ^ hy0) & HASH_MASK) << 3)));
        const f32x2 e11 = *(const f32x2*)(ebase + (lb + (((ux1 ^ hy1) & HASH_MASK) << 3)));
        const float owx = 1.f - wx, owy = 1.f - wy;
        const float f0 = (e00.x * owx + e10.x * wx) * owy + (e01.x * owx + e11.x * wx) * wy;
        const float f1 = (e00.y * owx + e10.y * wx) * owy + (e01.y * owx + e11.y * wx) * wy;
        vv[i] = pk_bf16(f0, f1);
    }
    uint2 v; v.x = vv[0]; v.y = vv[1];
    return v;
}

// ---- epilogue: bias + relu + bf16 pack, via packed f32 ops ----
__device__ __forceinline__ uint2 bias_relu_pk(const floatx4 a, const float4 bias)
{
    const f32x2 z = {0.f, 0.f};
    f32x2 v01 = {a[0], a[1]};
    f32x2 v23 = {a[2], a[3]};
    const f32x2 b01 = {bias.x, bias.y};
    const f32x2 b23 = {bias.z, bias.w};
    v01 += b01;                                    // v_pk_add_f32
    v23 += b23;
    v01 = __builtin_elementwise_max(v01, z);       // v_pk_max_f32
    v23 = __builtin_elementwise_max(v23, z);
    uint2 r;
    r.x = pk_bf16(v01.x, v01.y);
    r.y = pk_bf16(v23.x, v23.y);
    return r;
}

// ---------------- fused encoding + MLP ----------------
// 8 waves; each wave owns a 64-neuron x 32-point C-tile -> acc[4][2] = 32
// accumulator regs (was 64). The unified VGPR+AGPR file was the occupancy
// cap at 4 waves/SIMD; this targets 6 waves/SIMD (24 waves/CU, 3 blocks).
__global__ __launch_bounds__(TPB, 6)
void fused_ngp_mlp(const float2* __restrict__ xy,
                   const float* __restrict__ emb,
                   const unsigned short* __restrict__ wpack,
                   const float* __restrict__ b0,
                   const float* __restrict__ b1,
                   const float* __restrict__ b2,
                   float* __restrict__ out, int npoints)
{
    // single 32 KB buffer: feat (8 KB, XOR-swizzled [64][128B]) overlays the
    // low bytes of h ([64][512B], h0 then h1). Overlay is safe: an extra
    // barrier separates the last feat read (phase-2 kt loop) from the first
    // h0 write (phase-2 epilogue).
    __shared__ __attribute__((aligned(16))) unsigned char h[BT * 512];      // 32 KB
    unsigned char* feat = h;

    const int t = threadIdx.x;
    const int p0 = blockIdx.x * BT;
    const int wave = t >> 6;
    const int lane = t & 63;
    const int q = lane >> 4, r = lane & 15;
    const int wn = wave & 3;   // neuron-quarter (64 neurons)
    const int wp = wave >> 2;  // point-half (32 points)

    // ---------- phase 1a: x,y + zero fill (bytes 64..127 of each feat row) ----------
    {
        const int p = t >> 3;          // 0..63
        const int sg = t & 7;          // 0..7, 8 B each
        uint2 z = {0u, 0u};
        if (sg == 0) {
            const int gp = p0 + p;
            float x = 0.f, y = 0.f;
            if (gp < npoints) {
                const float2 c = xy[gp];
                x = fminf(fmaxf(c.x, -1.f), 1.f);
                y = fminf(fmaxf(c.y, -1.f), 1.f);
            }
            z.x = pk_bf16(x, y);
        }
        *(uint2*)(feat + fswz(p, 64 + 8 * sg)) = z;
    }

    // ---------- phase 1b: hash-grid gathers; wave w -> levels 2w,2w+1, point = lane ----------
    {
        const int gp = p0 + lane;
        float x = 0.f, y = 0.f;
        if (gp < npoints) {
            const float2 c = xy[gp];
            x = fminf(fmaxf(c.x, -1.f), 1.f);
            y = fminf(fmaxf(c.y, -1.f), 1.f);
        }
        const char* ebase = (const char*)emb;
        uint2 v;
        switch (wave) {
            case 0:  v = encode2<0>(x, y, ebase); break;
            case 1:  v = encode2<1>(x, y, ebase); break;
            case 2:  v = encode2<2>(x, y, ebase); break;
            case 3:  v = encode2<3>(x, y, ebase); break;
            case 4:  v = encode2<4>(x, y, ebase); break;
            case 5:  v = encode2<5>(x, y, ebase); break;
            case 6:  v = encode2<6>(x, y, ebase); break;
            default: v = encode2<7>(x, y, ebase); break;
        }
        *(uint2*)(feat + fswz(lane, 8 * wave)) = v;   // 8 B: levels 2w, 2w+1
    }
    __syncthreads();

    const unsigned short* w0p = wpack;
    const unsigned short* w1p = wpack + 32 * 1024;
    const unsigned short* w2p = wpack + 160 * 1024;

    // ---------- phase 2: layer 0 (K=64 padded), W^T x feat^T -> h0[point][neuron] ----------
    {
        floatx4 acc[4][2];   // [mti (neuron tile)][nt (point tile)]
        #pragma unroll
        for (int mti = 0; mti < 4; ++mti)
            #pragma unroll
            for (int nt = 0; nt < 2; ++nt)
                acc[mti][nt] = floatx4{0.f, 0.f, 0.f, 0.f};
        #pragma unroll
        for (int kt = 0; kt < 2; ++kt) {
            short8 b[2];
            #pragma unroll
            for (int nt = 0; nt < 2; ++nt)
                b[nt] = *(const short8*)(feat + fswz((wp * 2 + nt) * 16 + r, 64 * kt + 16 * q));
            #pragma unroll
            for (int mti = 0; mti < 4; ++mti) {
                const short8 a = *(const short8*)(w0p + (size_t)(kt * 16 + wn * 4 + mti) * 1024 + lane * 8);
                #pragma unroll
                for (int nt = 0; nt < 2; ++nt)
                    acc[mti][nt] = __builtin_amdgcn_mfma_f32_16x16x32_bf16(a, b[nt], acc[mti][nt], 0, 0, 0);
            }
        }
        __syncthreads();   // all feat reads done before h0 overwrites the overlay
        // C[m=neuron=(wn*4+mti)*16+4q+reg][n=point=(wp*2+nt)*16+r]
        #pragma unroll
        for (int mti = 0; mti < 4; ++mti) {
            const int col = (wn * 4 + mti) * 16 + 4 * q;
            const float4 bias = *(const float4*)&b0[col];
            #pragma unroll
            for (int nt = 0; nt < 2; ++nt) {
                const uint2 v = bias_relu_pk(acc[mti][nt], bias);
                *(uint2*)(h + hswz((wp * 2 + nt) * 16 + r, 2 * col)) = v;
            }
        }
    }
    __syncthreads();

    // ---------- phase 3: layer 1 (256 -> 256) ----------
    {
        floatx4 acc[4][2];
        #pragma unroll
        for (int mti = 0; mti < 4; ++mti)
            #pragma unroll
            for (int nt = 0; nt < 2; ++nt)
                acc[mti][nt] = floatx4{0.f, 0.f, 0.f, 0.f};
        #pragma unroll 2
        for (int kt = 0; kt < 8; ++kt) {
            short8 b[2];
            #pragma unroll
            for (int nt = 0; nt < 2; ++nt)
                b[nt] = *(const short8*)(h + hswz((wp * 2 + nt) * 16 + r, 64 * kt + 16 * q));
            #pragma unroll
            for (int mti = 0; mti < 4; ++mti) {
                const short8 a = *(const short8*)(w1p + (size_t)(kt * 16 + wn * 4 + mti) * 1024 + lane * 8);
                #pragma unroll
                for (int nt = 0; nt < 2; ++nt)
                    acc[mti][nt] = __builtin_amdgcn_mfma_f32_16x16x32_bf16(a, b[nt], acc[mti][nt], 0, 0, 0);
            }
        }
        __syncthreads();   // all reads of h0 done before overwrite
        #pragma unroll
        for (int mti = 0; mti < 4; ++mti) {
            const int col = (wn * 4 + mti) * 16 + 4 * q;
            const float4 bias = *(const float4*)&b1[col];
            #pragma unroll
            for (int nt = 0; nt < 2; ++nt) {
                const uint2 v = bias_relu_pk(acc[mti][nt], bias);
                *(uint2*)(h + hswz((wp * 2 + nt) * 16 + r, 2 * col)) = v;
            }
        }
    }
    __syncthreads();

    // ---------- phase 4: layer 2 (256 -> 3), sigmoid, store (waves 0-3) ----------
    if (wave < 4) {
        floatx4 acc = floatx4{0.f, 0.f, 0.f, 0.f};
        #pragma unroll
        for (int kt = 0; kt < 8; ++kt) {
            const short8 a = *(const short8*)(w2p + (size_t)kt * 1024 + lane * 8);
            const short8 b = *(const short8*)(h + hswz(16 * wave + r, 64 * kt + 16 * q));
            acc = __builtin_amdgcn_mfma_f32_16x16x32_bf16(a, b, acc, 0, 0, 0);
        }
        // C[m=4q+reg][n=16*wave+r]: only q==0, reg<3 are real outputs
        if (q == 0) {
            const int gp = p0 + 16 * wave + r;
            if (gp < npoints) {
                #pragma unroll
                for (int reg = 0; reg < 3; ++reg) {
                    const float s = acc[reg] + b2[reg];
                    out[(size_t)gp * 3 + reg] = 1.f / (1.f + expf(-s));
                }
            }
        }
    }
}

extern "C" void kernel_launch(void* const* d_in, const int* in_sizes, int n_in,
                              void* d_out, int out_size, void* d_ws, size_t ws_size,
                              hipStream_t stream) {
    const float* coord = (const float*)d_in[0];
    const float* emb   = (const float*)d_in[1];
    const float* W0    = (const float*)d_in[2];
    const float* b0    = (const float*)d_in[3];
    const float* W1    = (const float*)d_in[4];
    const float* b1    = (const float*)d_in[5];
    const float* W2    = (const float*)d_in[6];
    const float* b2    = (const float*)d_in[7];
    float* out = (float*)d_out;
    unsigned short* ws = (unsigned short*)d_ws;

    const int npoints = in_sizes[0] / 2;
    const int blocks  = (npoints + BT - 1) / BT;

    hipLaunchKernelGGL(pack_weights, dim3(168), dim3(64), 0, stream, W0, W1, W2, ws);
    hipLaunchKernelGGL(fused_ngp_mlp, dim3(blocks), dim3(TPB), 0, stream,
                       (const float2*)coord, emb, ws, b0, b1, b2, out, npoints);
}

// Round 7
// 364.854 us; speedup vs baseline: 1.1752x; 1.1752x over previous
//
#include <hip/hip_runtime.h>
#include <hip/hip_bf16.h>
#include <cstdint>
#include <cstddef>

#define N_LEVELS   16
#define LOG2_T     19
#define TABLE_SIZE (1u << LOG2_T)
#define HASH_MASK  (TABLE_SIZE - 1u)
#define PRIME1     2654435761u

#define TPB 512
#define BT  64          // points per block

typedef __attribute__((ext_vector_type(8))) short short8;
typedef __attribute__((ext_vector_type(4))) float floatx4;
typedef __attribute__((ext_vector_type(2))) float f32x2;

// floor(16 * (2^(1/3))^l) in fp32 lands exactly on these integers
__device__ __forceinline__ constexpr float resf(int l) {
    constexpr float r[N_LEVELS] = {
        16.f, 20.f, 25.f, 32.f, 40.f, 50.f, 64.f, 80.f,
        101.f, 128.f, 161.f, 203.f, 256.f, 322.f, 406.f, 512.f
    };
    return r[l];
}

__device__ __forceinline__ unsigned short f2bf(float x) {
    union { float f; uint32_t u; } v; v.f = x;
    const uint32_t u = v.u;
    return (unsigned short)((u + 0x7fffu + ((u >> 16) & 1u)) >> 16);  // RNE
}

__device__ __forceinline__ uint32_t pk_bf16(float a, float b) {
#if __has_builtin(__builtin_amdgcn_cvt_pk_bf16_f32)
    typedef __attribute__((ext_vector_type(2))) __bf16 bf16x2;
    bf16x2 v = __builtin_amdgcn_cvt_pk_bf16_f32(a, b);
    uint32_t u; __builtin_memcpy(&u, &v, 4); return u;
#else
    return (uint32_t)f2bf(a) | ((uint32_t)f2bf(b) << 16);
#endif
}

// ---- XOR-swizzled LDS byte offsets ----
// (R5 lesson: banks wrap every 128 B; ~2e7 conflict cycles are structural to
// wave64 ds_read_b128. Don't chase below this level.)
__device__ __forceinline__ int fswz(int row, int cb) {   // feat: 128 B/row
    return (row << 7) + (cb ^ ((row & 7) << 4));
}
__device__ __forceinline__ int hswz(int row, int cb) {   // h: 512 B/row
    const int c = row & 7;
    return (row << 9) + (cb ^ ((c << 4) ^ (c << 6)));
}

// ---------------- weight packing into MFMA fragments ----------------
// Fragment for (tile, ktile): lane (q=l>>4, r=l&15) holds W[k = kt*32 + q*8 + j][col = tile*16 + r].
__global__ void pack_weights(const float* __restrict__ W0,
                             const float* __restrict__ W1,
                             const float* __restrict__ W2,
                             unsigned short* __restrict__ ws)
{
    const int f = blockIdx.x;       // 0..167
    const int lane = threadIdx.x;   // 0..63
    const int q = lane >> 4, r = lane & 15;
    int layer, kt, nt;
    if (f < 32)       { layer = 0; kt = f >> 4;        nt = f & 15; }
    else if (f < 160) { layer = 1; kt = (f - 32) >> 4; nt = (f - 32) & 15; }
    else              { layer = 2; kt = f - 160;       nt = 0; }
    unsigned short vals[8];
    #pragma unroll
    for (int j = 0; j < 8; ++j) {
        const int k = kt * 32 + q * 8 + j;
        const int n = nt * 16 + r;
        float v = 0.f;
        if (layer == 0) {
            // feat order: [enc0..enc31, x, y, zeros]; original W0 rows: [x, y, enc0..enc31]
            if (k < 32)       v = W0[(2 + k) * 256 + n];
            else if (k == 32) v = W0[0 * 256 + n];
            else if (k == 33) v = W0[1 * 256 + n];
        } else if (layer == 1) {
            v = W1[k * 256 + n];
        } else {
            if (n < 3) v = W2[k * 3 + n];
        }
        vals[j] = f2bf(v);
    }
    uint4 pk;
    pk.x = (uint32_t)vals[0] | ((uint32_t)vals[1] << 16);
    pk.y = (uint32_t)vals[2] | ((uint32_t)vals[3] << 16);
    pk.z = (uint32_t)vals[4] | ((uint32_t)vals[5] << 16);
    pk.w = (uint32_t)vals[6] | ((uint32_t)vals[7] << 16);
    *(uint4*)(ws + (size_t)f * 1024 + lane * 8) = pk;
}

// ---- phase-1 encode: 2 levels (2W, 2W+1) for one point, compile-time W ----
template<int W>
__device__ __forceinline__ uint2 encode2(float x, float y, const char* __restrict__ ebase)
{
    uint32_t vv[2];
    #pragma unroll
    for (int i = 0; i < 2; ++i) {
        const int l = 2 * W + i;
        const float res  = resf(l);
        const float grid = 2.0f / res;             // constexpr IEEE div (matches ref)
        const float invg = res * 0.5f;             // exact
        const float tx = (x + 1.0f) / grid;        // IEEE div feeds floor -> exact cell match
        const float ty = (y + 1.0f) / grid;
        const int bx = (int)floorf(tx);
        const int by = (int)floorf(ty);
        const float wx = (x - ((float)bx * grid - 1.0f)) * invg;
        const float wy = (y - ((float)by * grid - 1.0f)) * invg;
        const uint32_t hy0 = (uint32_t)by * PRIME1;
        const uint32_t hy1 = hy0 + PRIME1;         // (by+1)*P mod 2^32
        const uint32_t ux0 = (uint32_t)bx;
        const uint32_t ux1 = ux0 + 1u;
        const uint32_t lb = (uint32_t)l << (LOG2_T + 3);   // level table byte base
        const f32x2 e00 = *(const f32x2*)(ebase + (lb + (((ux0 ^ hy0) & HASH_MASK) << 3)));
        const f32x2 e01 = *(const f32x2*)(ebase + (lb + (((ux0 ^ hy1) & HASH_MASK) << 3)));
        const f32x2 e10 = *(const f32x2*)(ebase + (lb + (((ux1 ^ hy0) & HASH_MASK) << 3)));
        const f32x2 e11 = *(const f32x2*)(ebase + (lb + (((ux1 ^ hy1) & HASH_MASK) << 3)));
        const float owx = 1.f - wx, owy = 1.f - wy;
        const float f0 = (e00.x * owx + e10.x * wx) * owy + (e01.x * owx + e11.x * wx) * wy;
        const float f1 = (e00.y * owx + e10.y * wx) * owy + (e01.y * owx + e11.y * wx) * wy;
        vv[i] = pk_bf16(f0, f1);
    }
    uint2 v; v.x = vv[0]; v.y = vv[1];
    return v;
}

// ---- epilogue: bias + relu + bf16 pack, via packed f32 ops ----
__device__ __forceinline__ uint2 bias_relu_pk(const floatx4 a, const float4 bias)
{
    const f32x2 z = {0.f, 0.f};
    f32x2 v01 = {a[0], a[1]};
    f32x2 v23 = {a[2], a[3]};
    const f32x2 b01 = {bias.x, bias.y};
    const f32x2 b23 = {bias.z, bias.w};
    v01 += b01;                                    // v_pk_add_f32
    v23 += b23;
    v01 = __builtin_elementwise_max(v01, z);       // v_pk_max_f32
    v23 = __builtin_elementwise_max(v23, z);
    uint2 r;
    r.x = pk_bf16(v01.x, v01.y);
    r.y = pk_bf16(v23.x, v23.y);
    return r;
}

// ---------------- fused encoding + MLP ----------------
// 8 waves; each wave owns a 32-neuron x 64-point C-tile (acc[2][4] = 32
// accumulator regs). Neuron-split (not point-split, R6's mistake): every
// weight fragment is read by exactly ONE wave -> per-block weight traffic
// through L1 stays 1x (R6's point-split doubled it: 286 -> 378 us).
// Cost shifted to LDS: each b-frag is read by 2 waves (LDS has the headroom).
__global__ __launch_bounds__(TPB, 4)
void fused_ngp_mlp(const float2* __restrict__ xy,
                   const float* __restrict__ emb,
                   const unsigned short* __restrict__ wpack,
                   const float* __restrict__ b0,
                   const float* __restrict__ b1,
                   const float* __restrict__ b2,
                   float* __restrict__ out, int npoints)
{
    // single 32 KB buffer: feat (8 KB, XOR-swizzled [64][128B]) overlays the
    // low bytes of h ([64][512B], h0 then h1). Overlay safe: a barrier
    // separates the last feat read (phase-2 kt loop) from the first h0 write.
    __shared__ __attribute__((aligned(16))) unsigned char h[BT * 512];      // 32 KB
    unsigned char* feat = h;

    const int t = threadIdx.x;
    const int p0 = blockIdx.x * BT;
    const int wave = t >> 6;   // 0..7: neuron-eighth (32 neurons each)
    const int lane = t & 63;
    const int q = lane >> 4, r = lane & 15;

    // ---------- phase 1a: x,y + zero fill (bytes 64..127 of each feat row) ----------
    {
        const int p = t >> 3;          // 0..63
        const int sg = t & 7;          // 0..7, 8 B each
        uint2 z = {0u, 0u};
        if (sg == 0) {
            const int gp = p0 + p;
            float x = 0.f, y = 0.f;
            if (gp < npoints) {
                const float2 c = xy[gp];
                x = fminf(fmaxf(c.x, -1.f), 1.f);
                y = fminf(fmaxf(c.y, -1.f), 1.f);
            }
            z.x = pk_bf16(x, y);
        }
        *(uint2*)(feat + fswz(p, 64 + 8 * sg)) = z;
    }

    // ---------- phase 1b: hash-grid gathers; wave w -> levels 2w,2w+1, point = lane ----------
    {
        const int gp = p0 + lane;
        float x = 0.f, y = 0.f;
        if (gp < npoints) {
            const float2 c = xy[gp];
            x = fminf(fmaxf(c.x, -1.f), 1.f);
            y = fminf(fmaxf(c.y, -1.f), 1.f);
        }
        const char* ebase = (const char*)emb;
        uint2 v;
        switch (wave) {
            case 0:  v = encode2<0>(x, y, ebase); break;
            case 1:  v = encode2<1>(x, y, ebase); break;
            case 2:  v = encode2<2>(x, y, ebase); break;
            case 3:  v = encode2<3>(x, y, ebase); break;
            case 4:  v = encode2<4>(x, y, ebase); break;
            case 5:  v = encode2<5>(x, y, ebase); break;
            case 6:  v = encode2<6>(x, y, ebase); break;
            default: v = encode2<7>(x, y, ebase); break;
        }
        *(uint2*)(feat + fswz(lane, 8 * wave)) = v;   // 8 B: levels 2w, 2w+1
    }
    __syncthreads();

    const unsigned short* w0p = wpack;
    const unsigned short* w1p = wpack + 32 * 1024;
    const unsigned short* w2p = wpack + 160 * 1024;

    // ---------- phase 2: layer 0 (K=64 padded), W^T x feat^T -> h0[point][neuron] ----------
    {
        floatx4 acc[2][4];   // [mti (neuron tile)][nt (point tile)]
        #pragma unroll
        for (int mti = 0; mti < 2; ++mti)
            #pragma unroll
            for (int nt = 0; nt < 4; ++nt)
                acc[mti][nt] = floatx4{0.f, 0.f, 0.f, 0.f};
        #pragma unroll
        for (int kt = 0; kt < 2; ++kt) {
            short8 b[4];
            #pragma unroll
            for (int nt = 0; nt < 4; ++nt)
                b[nt] = *(const short8*)(feat + fswz(16 * nt + r, 64 * kt + 16 * q));
            #pragma unroll
            for (int mti = 0; mti < 2; ++mti) {
                const short8 a = *(const short8*)(w0p + (size_t)(kt * 16 + wave * 2 + mti) * 1024 + lane * 8);
                #pragma unroll
                for (int nt = 0; nt < 4; ++nt)
                    acc[mti][nt] = __builtin_amdgcn_mfma_f32_16x16x32_bf16(a, b[nt], acc[mti][nt], 0, 0, 0);
            }
        }
        __syncthreads();   // all feat reads done before h0 overwrites the overlay
        // C[m=neuron=(wave*2+mti)*16+4q+reg][n=point=16nt+r]
        #pragma unroll
        for (int mti = 0; mti < 2; ++mti) {
            const int col = (wave * 2 + mti) * 16 + 4 * q;
            const float4 bias = *(const float4*)&b0[col];
            #pragma unroll
            for (int nt = 0; nt < 4; ++nt) {
                const uint2 v = bias_relu_pk(acc[mti][nt], bias);
                *(uint2*)(h + hswz(16 * nt + r, 2 * col)) = v;
            }
        }
    }
    __syncthreads();

    // ---------- phase 3: layer 1 (256 -> 256) ----------
    {
        floatx4 acc[2][4];
        #pragma unroll
        for (int mti = 0; mti < 2; ++mti)
            #pragma unroll
            for (int nt = 0; nt < 4; ++nt)
                acc[mti][nt] = floatx4{0.f, 0.f, 0.f, 0.f};
        #pragma unroll 2
        for (int kt = 0; kt < 8; ++kt) {
            short8 b[4];
            #pragma unroll
            for (int nt = 0; nt < 4; ++nt)
                b[nt] = *(const short8*)(h + hswz(16 * nt + r, 64 * kt + 16 * q));
            #pragma unroll
            for (int mti = 0; mti < 2; ++mti) {
                const short8 a = *(const short8*)(w1p + (size_t)(kt * 16 + wave * 2 + mti) * 1024 + lane * 8);
                #pragma unroll
                for (int nt = 0; nt < 4; ++nt)
                    acc[mti][nt] = __builtin_amdgcn_mfma_f32_16x16x32_bf16(a, b[nt], acc[mti][nt], 0, 0, 0);
            }
        }
        __syncthreads();   // all reads of h0 done before overwrite
        #pragma unroll
        for (int mti = 0; mti < 2; ++mti) {
            const int col = (wave * 2 + mti) * 16 + 4 * q;
            const float4 bias = *(const float4*)&b1[col];
            #pragma unroll
            for (int nt = 0; nt < 4; ++nt) {
                const uint2 v = bias_relu_pk(acc[mti][nt], bias);
                *(uint2*)(h + hswz(16 * nt + r, 2 * col)) = v;
            }
        }
    }
    __syncthreads();

    // ---------- phase 4: layer 2 (256 -> 3), sigmoid, store (waves 0-3) ----------
    if (wave < 4) {
        floatx4 acc = floatx4{0.f, 0.f, 0.f, 0.f};
        #pragma unroll
        for (int kt = 0; kt < 8; ++kt) {
            const short8 a = *(const short8*)(w2p + (size_t)kt * 1024 + lane * 8);
            const short8 b = *(const short8*)(h + hswz(16 * wave + r, 64 * kt + 16 * q));
            acc = __builtin_amdgcn_mfma_f32_16x16x32_bf16(a, b, acc, 0, 0, 0);
        }
        // C[m=4q+reg][n=16*wave+r]: only q==0, reg<3 are real outputs
        if (q == 0) {
            const int gp = p0 + 16 * wave + r;
            if (gp < npoints) {
                #pragma unroll
                for (int reg = 0; reg < 3; ++reg) {
                    const float s = acc[reg] + b2[reg];
                    out[(size_t)gp * 3 + reg] = 1.f / (1.f + expf(-s));
                }
            }
        }
    }
}

extern "C" void kernel_launch(void* const* d_in, const int* in_sizes, int n_in,
                              void* d_out, int out_size, void* d_ws, size_t ws_size,
                              hipStream_t stream) {
    const float* coord = (const float*)d_in[0];
    const float* emb   = (const float*)d_in[1];
    const float* W0    = (const float*)d_in[2];
    const float* b0    = (const float*)d_in[3];
    const float* W1    = (const float*)d_in[4];
    const float* b1    = (const float*)d_in[5];
    const float* W2    = (const float*)d_in[6];
    const float* b2    = (const float*)d_in[7];
    float* out = (float*)d_out;
    unsigned short* ws = (unsigned short*)d_ws;

    const int npoints = in_sizes[0] / 2;
    const int blocks  = (npoints + BT - 1) / BT;

    hipLaunchKernelGGL(pack_weights, dim3(168), dim3(64), 0, stream, W0, W1, W2, ws);
    hipLaunchKernelGGL(fused_ngp_mlp, dim3(blocks), dim3(TPB), 0, stream,
                       (const float2*)coord, emb, ws, b0, b1, b2, out, npoints);
}